// Round 4
// baseline (415.139 us; speedup 1.0000x reference)
//
#include <hip/hip_runtime.h>
#include <math.h>

#define ALPHA 0.2f

typedef __attribute__((ext_vector_type(8))) short bf16x8;
typedef __attribute__((ext_vector_type(4))) float f32x4;

static __device__ __forceinline__ float lrelu(float v) {
    return v > 0.0f ? v : ALPHA * v;
}
// fp32 -> bf16 round-to-nearest-even
static __device__ __forceinline__ uint16_t f2b(float f) {
    union { float f; uint32_t u; } c; c.f = f;
    const uint32_t u = c.u + 0x7FFFu + ((c.u >> 16) & 1u);
    return (uint16_t)(u >> 16);
}
static __device__ __forceinline__ uint32_t pk2(float a, float b) {
    return (uint32_t)f2b(a) | ((uint32_t)f2b(b) << 16);
}
static __device__ __forceinline__ float b2f16(uint16_t h) {
    union { uint32_t u; float f; } c; c.u = ((uint32_t)h) << 16; return c.f;
}

// ---------------- precompute: tables + bf16 weights (once per call) --------
// blocks 0..99  : per-row tables (64 rows each):
//   base0T[r][o] = b0[o] + W0[o][0:32].x_r     (fp32)
//   GT[r][o]     = W0[o][32:64].x_r            (fp32)
//   xyt[r]       = x_r[0:2];  hin[r][192..224] = x_r  (node-input tail)
// blocks 100..127: bf16 casts of W1,W2,Fn0,Fn1 + wd0 = W0[:,64]
__global__ __launch_bounds__(256) void precompute(
    const float* __restrict__ x, const float* __restrict__ w0,
    const float* __restrict__ b0, const float* __restrict__ w1,
    const float* __restrict__ w2, const float* __restrict__ f0,
    const float* __restrict__ f1,
    float* __restrict__ base0T, float* __restrict__ GT,
    float* __restrict__ xyt, float* __restrict__ wd0,
    uint16_t* __restrict__ wb1, uint16_t* __restrict__ wb2,
    uint16_t* __restrict__ wfn0, uint16_t* __restrict__ wfn1,
    float* __restrict__ hin)
{
    const int blk = blockIdx.x, t = threadIdx.x;
    if (blk >= 100) {
        const int t0 = (blk - 100) * 256 + t;  // 0..7167
        for (int i = t0; i < 160 * 96;  i += 7168) wb1[i]  = f2b(w1[i]);
        for (int i = t0; i < 192 * 160; i += 7168) wb2[i]  = f2b(w2[i]);
        for (int i = t0; i < 256 * 224; i += 7168) wfn0[i] = f2b(f0[i]);
        for (int i = t0; i < 256 * 256; i += 7168) wfn1[i] = f2b(f1[i]);
        if (t0 < 96) wd0[t0] = w0[t0 * 65 + 64];
        return;
    }
    __shared__ float W0s[96 * 65];
    __shared__ float xs[64 * 32];
    const int r0 = blk * 64;
    for (int i = t; i < 96 * 65; i += 256) W0s[i] = w0[i];
    for (int i = t; i < 2048; i += 256) xs[i] = x[(size_t)r0 * 32 + i];
    __syncthreads();
    for (int it = 0; it < 48; ++it) {              // 64 rows * 192 outs
        const int out = t + 256 * it;
        const int row = out / 192, oi = out - row * 192;
        const int o = (oi < 96) ? oi : oi - 96;
        const float* wr = W0s + o * 65 + ((oi < 96) ? 0 : 32);
        const float* xr = xs + row * 32;
        float a = (oi < 96) ? b0[o] : 0.0f;
#pragma unroll
        for (int k = 0; k < 32; ++k) a += wr[k] * xr[k];
        if (oi < 96) base0T[(size_t)(r0 + row) * 96 + o] = a;
        else         GT[(size_t)(r0 + row) * 96 + o] = a;
    }
    for (int i = t; i < 128; i += 256)
        xyt[(r0 + (i >> 1)) * 2 + (i & 1)] = xs[(i >> 1) * 32 + (i & 1)];
    for (int i = t; i < 2048; i += 256)
        hin[(size_t)(r0 + (i >> 5)) * 256 + 192 + (i & 31)] = xs[i];
}

// ---------------- edge kernel: one block per (b,i) -------------------------
// H1[112][96] (stride 104) built elementwise from tables; L2/L3 MFMA in
// 3 m-subsets {48,48,16} sharing H2l[48][168].  LDS 40.2 KB -> 4 blocks/CU.
__global__ __launch_bounds__(256, 4) void edge_kernel(
    const float* __restrict__ base0T, const float* __restrict__ GT,
    const float* __restrict__ xyt, const float* __restrict__ wd0,
    const float* __restrict__ b1f, const float* __restrict__ eb2,
    const uint16_t* __restrict__ wb1, const uint16_t* __restrict__ wb2,
    float* __restrict__ hin)
{
    __shared__ __align__(16) uint16_t H1[112 * 104];   // 23296 B
    __shared__ __align__(16) uint16_t H2l[48 * 168];   // 16128 B
    __shared__ __align__(16) float b0wd[192];          // 768 B

    const int bi = blockIdx.x, b = bi / 100;
    const int t = threadIdx.x;
    const int lane = t & 63, wave = t >> 6;
    const int col = lane & 15, g = lane >> 4;

    if (t < 96) b0wd[t] = base0T[(size_t)bi * 96 + t];
    else if (t < 192) b0wd[t] = wd0[t - 96];
    const float xix = xyt[bi * 2 + 0], xiy = xyt[bi * 2 + 1];
    __syncthreads();

    // ---- H1 build: H1[j][o] = bf16(lrelu(G[j][o] + base0[o] + wd[o]*d_j))
    for (int it = 0; it < 11; ++it) {
        const int q = t + 256 * it;
        if (q < 2688) {                       // 112 rows * 24 o-quads
            const int j = q / 24, o4 = q - j * 24;
            uint32_t lo = 0, hi = 0;
            if (j < 100) {
                const float4 gv = *(const float4*)(GT + (size_t)(b * 100 + j) * 96 + o4 * 4);
                const float2 p = *(const float2*)(xyt + (b * 100 + j) * 2);
                const float dx = p.x - xix + 1e-12f, dy = p.y - xiy + 1e-12f;
                const float d = sqrtf(dx * dx + dy * dy);
                const float4 bb = *(const float4*)(b0wd + o4 * 4);
                const float4 wv = *(const float4*)(b0wd + 96 + o4 * 4);
                lo = pk2(lrelu(gv.x + bb.x + wv.x * d), lrelu(gv.y + bb.y + wv.y * d));
                hi = pk2(lrelu(gv.z + bb.z + wv.z * d), lrelu(gv.w + bb.w + wv.w * d));
            }
            *(uint2*)(H1 + j * 104 + o4 * 4) = (uint2){lo, hi};
        }
    }
    __syncthreads();

    float* hinrow = hin + (size_t)bi * 256;
    float ssum[3] = {0.f, 0.f, 0.f};
#pragma unroll
    for (int sub = 0; sub < 3; ++sub) {
        const int MT = (sub < 2) ? 3 : 1;
        {   // ---- L2: H2l = lrelu(H1[sub rows] @ W1^T + b1) ----
            f32x4 acc[3][3];
#pragma unroll
            for (int s = 0; s < 3; ++s) {
                const int nt = wave + 4 * s;
                if (nt < 10) {
                    const float bv = b1f[nt * 16 + col];
#pragma unroll
                    for (int m = 0; m < 3; ++m) if (m < MT)
                        acc[s][m] = (f32x4){bv, bv, bv, bv};
                }
            }
            __builtin_amdgcn_s_setprio(1);
#pragma unroll
            for (int kt = 0; kt < 3; ++kt) {
                bf16x8 bfr[3];
#pragma unroll
                for (int s = 0; s < 3; ++s) {
                    const int nt = wave + 4 * s;
                    if (nt < 10)
                        bfr[s] = *(const bf16x8*)(wb1 + (size_t)(nt * 16 + col) * 96 + kt * 32 + 8 * g);
                }
#pragma unroll
                for (int m = 0; m < 3; ++m) if (m < MT) {
                    const bf16x8 af = *(const bf16x8*)(H1 + (sub * 48 + m * 16 + col) * 104 + kt * 32 + 8 * g);
#pragma unroll
                    for (int s = 0; s < 3; ++s) {
                        const int nt = wave + 4 * s;
                        if (nt < 10)
                            acc[s][m] = __builtin_amdgcn_mfma_f32_16x16x32_bf16(af, bfr[s], acc[s][m], 0, 0, 0);
                    }
                }
            }
            __builtin_amdgcn_s_setprio(0);
#pragma unroll
            for (int s = 0; s < 3; ++s) {
                const int nt = wave + 4 * s;
                if (nt < 10) {
#pragma unroll
                    for (int m = 0; m < 3; ++m) if (m < MT)
#pragma unroll
                        for (int r = 0; r < 4; ++r)
                            H2l[(m * 16 + 4 * g + r) * 168 + nt * 16 + col] =
                                f2b(lrelu(acc[s][m][r]));
                }
            }
        }
        __syncthreads();
        {   // ---- L3 partial: ssum += masked row-sums of lrelu(H2l @ W2^T + b2)
            f32x4 acc[3][3];
#pragma unroll
            for (int s = 0; s < 3; ++s) {
                const float bv = eb2[(wave + 4 * s) * 16 + col];
#pragma unroll
                for (int m = 0; m < 3; ++m) if (m < MT)
                    acc[s][m] = (f32x4){bv, bv, bv, bv};
            }
            __builtin_amdgcn_s_setprio(1);
#pragma unroll
            for (int kt = 0; kt < 5; ++kt) {
                bf16x8 bfr[3];
#pragma unroll
                for (int s = 0; s < 3; ++s)
                    bfr[s] = *(const bf16x8*)(wb2 + (size_t)((wave + 4 * s) * 16 + col) * 160 + kt * 32 + 8 * g);
#pragma unroll
                for (int m = 0; m < 3; ++m) if (m < MT) {
                    const bf16x8 af = *(const bf16x8*)(H2l + (m * 16 + col) * 168 + kt * 32 + 8 * g);
#pragma unroll
                    for (int s = 0; s < 3; ++s)
                        acc[s][m] = __builtin_amdgcn_mfma_f32_16x16x32_bf16(af, bfr[s], acc[s][m], 0, 0, 0);
                }
            }
            __builtin_amdgcn_s_setprio(0);
#pragma unroll
            for (int s = 0; s < 3; ++s) {
                float ps = 0.0f;
#pragma unroll
                for (int m = 0; m < 3; ++m) if (m < MT) {
                    const int rowbase = sub * 48 + m * 16 + 4 * g;
#pragma unroll
                    for (int r = 0; r < 4; ++r)
                        if (sub < 2 || (rowbase + r < 100)) ps += lrelu(acc[s][m][r]);
                }
                ssum[s] += ps;
            }
        }
        if (sub < 2) __syncthreads();
    }
#pragma unroll
    for (int s = 0; s < 3; ++s) {
        float v = ssum[s];
        v += __shfl_xor(v, 16);
        v += __shfl_xor(v, 32);
        if (lane < 16) hinrow[(wave + 4 * s) * 16 + col] = v;
    }
}

// ---------------- fused node MLP: 16 rows per block, 400 blocks ------------
__global__ __launch_bounds__(256) void node_kernel(
    const float* __restrict__ hin,
    const uint16_t* __restrict__ wfn0, const float* __restrict__ fb0,
    const uint16_t* __restrict__ wfn1, const float* __restrict__ fb1,
    const float* __restrict__ fw2, const float* __restrict__ fb2,
    float* __restrict__ out)
{
    __shared__ __align__(16) uint16_t RA[16 * 264];
    __shared__ __align__(16) uint16_t RH[16 * 264];
    const int t = threadIdx.x, lane = t & 63, wave = t >> 6;
    const int col = lane & 15, g = lane >> 4;
    const int r0 = blockIdx.x * 16;

    for (int r = wave; r < 16; r += 4) {
        const float* src = hin + (size_t)(r0 + r) * 256;
        for (int c = lane; c < 224; c += 64)
            RA[r * 232 + c] = f2b(src[c]);
    }
    __syncthreads();
    {   // L0: 224 -> 256
        f32x4 acc[4];
#pragma unroll
        for (int s = 0; s < 4; ++s) {
            const float bv = fb0[(wave + 4 * s) * 16 + col];
            acc[s] = (f32x4){bv, bv, bv, bv};
        }
#pragma unroll
        for (int kt = 0; kt < 7; ++kt) {
            const bf16x8 af = *(const bf16x8*)(RA + col * 232 + kt * 32 + 8 * g);
#pragma unroll
            for (int s = 0; s < 4; ++s) {
                const bf16x8 bfr = *(const bf16x8*)(
                    wfn0 + (size_t)((wave + 4 * s) * 16 + col) * 224 + kt * 32 + 8 * g);
                acc[s] = __builtin_amdgcn_mfma_f32_16x16x32_bf16(af, bfr, acc[s], 0, 0, 0);
            }
        }
#pragma unroll
        for (int s = 0; s < 4; ++s)
#pragma unroll
            for (int r = 0; r < 4; ++r)
                RH[(4 * g + r) * 264 + (wave + 4 * s) * 16 + col] = f2b(lrelu(acc[s][r]));
    }
    __syncthreads();
    {   // L1: 256 -> 256
        f32x4 acc[4];
#pragma unroll
        for (int s = 0; s < 4; ++s) {
            const float bv = fb1[(wave + 4 * s) * 16 + col];
            acc[s] = (f32x4){bv, bv, bv, bv};
        }
#pragma unroll
        for (int kt = 0; kt < 8; ++kt) {
            const bf16x8 af = *(const bf16x8*)(RH + col * 264 + kt * 32 + 8 * g);
#pragma unroll
            for (int s = 0; s < 4; ++s) {
                const bf16x8 bfr = *(const bf16x8*)(
                    wfn1 + (size_t)((wave + 4 * s) * 16 + col) * 256 + kt * 32 + 8 * g);
                acc[s] = __builtin_amdgcn_mfma_f32_16x16x32_bf16(af, bfr, acc[s], 0, 0, 0);
            }
        }
        __syncthreads();
#pragma unroll
        for (int s = 0; s < 4; ++s)
#pragma unroll
            for (int r = 0; r < 4; ++r)
                RA[(4 * g + r) * 264 + (wave + 4 * s) * 16 + col] = f2b(lrelu(acc[s][r]));
    }
    __syncthreads();
    // L2 final: 3 outputs fp32 + tanh
    const int row = t >> 4, u = t & 15;
    float h = 0.0f;
    if (u < 12) {
        const int o = u >> 2, ks = u & 3;
        const float* w = fw2 + o * 256 + ks * 64;
        const uint16_t* hr = RA + row * 264 + ks * 64;
        float a = 0.0f;
#pragma unroll 8
        for (int k = 0; k < 64; k += 4) {
            const ushort4 hv = *(const ushort4*)(hr + k);
            a += w[k + 0] * b2f16(hv.x) + w[k + 1] * b2f16(hv.y)
               + w[k + 2] * b2f16(hv.z) + w[k + 3] * b2f16(hv.w);
        }
        h = a;
    }
    h += __shfl_xor(h, 1);
    h += __shfl_xor(h, 2);
    if (u < 12 && (u & 3) == 0)
        out[(size_t)(r0 + row) * 3 + (u >> 2)] = tanhf(h + fb2[u >> 2]);
}

extern "C" void kernel_launch(void* const* d_in, const int* in_sizes, int n_in,
                              void* d_out, int out_size, void* d_ws, size_t ws_size,
                              hipStream_t stream) {
    (void)in_sizes; (void)n_in; (void)out_size; (void)ws_size;
    const float* x     = (const float*)d_in[0];
    const float* fe_w0 = (const float*)d_in[1];
    const float* fe_b0 = (const float*)d_in[2];
    const float* fe_w1 = (const float*)d_in[3];
    const float* fe_b1 = (const float*)d_in[4];
    const float* fe_w2 = (const float*)d_in[5];
    const float* fe_b2 = (const float*)d_in[6];
    const float* fn_w0 = (const float*)d_in[7];
    const float* fn_b0 = (const float*)d_in[8];
    const float* fn_w1 = (const float*)d_in[9];
    const float* fn_b1 = (const float*)d_in[10];
    const float* fn_w2 = (const float*)d_in[11];
    const float* fn_b2 = (const float*)d_in[12];
    float* out = (float*)d_out;

    float* buf0   = (float*)d_ws;                     // hin [6400][256] f32
    float* base0T = buf0 + (size_t)6400 * 256;        // 6400*96
    float* GT     = base0T + 6400 * 96;               // 6400*96
    float* xyt    = GT + 6400 * 96;                   // 6400*2
    float* wd0    = xyt + 12800;                      // 96 (pad 128)
    uint16_t* wb1  = (uint16_t*)(wd0 + 128);          // 160*96
    uint16_t* wb2  = wb1 + 160 * 96;                  // 192*160
    uint16_t* wfn0 = wb2 + 192 * 160;                 // 256*224
    uint16_t* wfn1 = wfn0 + 256 * 224;                // 256*256

    precompute<<<128, 256, 0, stream>>>(x, fe_w0, fe_b0, fe_w1, fe_w2,
                                        fn_w0, fn_w1,
                                        base0T, GT, xyt, wd0,
                                        wb1, wb2, wfn0, wfn1, buf0);
    edge_kernel<<<6400, 256, 0, stream>>>(base0T, GT, xyt, wd0,
                                          fe_b1, fe_b2, wb1, wb2, buf0);
    node_kernel<<<400, 256, 0, stream>>>(buf0, wfn0, fn_b0, wfn1, fn_b1,
                                         fn_w2, fn_b2, out);
}

// Round 5
// 216.249 us; speedup vs baseline: 1.9197x; 1.9197x over previous
//
#include <hip/hip_runtime.h>
#include <math.h>

#define ALPHA 0.2f

typedef __attribute__((ext_vector_type(8))) short bf16x8;
typedef __attribute__((ext_vector_type(4))) float f32x4;

static __device__ __forceinline__ float lrelu(float v) {
    return v > 0.0f ? v : ALPHA * v;
}
// fp32 -> bf16 round-to-nearest-even
static __device__ __forceinline__ uint16_t f2b(float f) {
    union { float f; uint32_t u; } c; c.f = f;
    const uint32_t u = c.u + 0x7FFFu + ((c.u >> 16) & 1u);
    return (uint16_t)(u >> 16);
}
static __device__ __forceinline__ uint32_t pk2(float a, float b) {
    return (uint32_t)f2b(a) | ((uint32_t)f2b(b) << 16);
}
static __device__ __forceinline__ float b2f16(uint16_t h) {
    union { uint32_t u; float f; } c; c.u = ((uint32_t)h) << 16; return c.f;
}

// ---------------- precompute: tables + bf16 weights (once per call) --------
// blocks 0..99  : per-row tables (64 rows each):
//   base0T[r][o] = b0[o] + W0[o][0:32].x_r     (fp32)
//   GT[r][o]     = W0[o][32:64].x_r            (fp32)
//   xyt[r]       = x_r[0:2];  hin[r][192..224] = x_r  (node-input tail)
// blocks 100..127: bf16 casts of W1,W2,Fn0,Fn1 + wd0 = W0[:,64]
__global__ __launch_bounds__(256) void precompute(
    const float* __restrict__ x, const float* __restrict__ w0,
    const float* __restrict__ b0, const float* __restrict__ w1,
    const float* __restrict__ w2, const float* __restrict__ f0,
    const float* __restrict__ f1,
    float* __restrict__ base0T, float* __restrict__ GT,
    float* __restrict__ xyt, float* __restrict__ wd0,
    uint16_t* __restrict__ wb1, uint16_t* __restrict__ wb2,
    uint16_t* __restrict__ wfn0, uint16_t* __restrict__ wfn1,
    float* __restrict__ hin)
{
    const int blk = blockIdx.x, t = threadIdx.x;
    if (blk >= 100) {
        const int t0 = (blk - 100) * 256 + t;  // 0..7167
        for (int i = t0; i < 160 * 96;  i += 7168) wb1[i]  = f2b(w1[i]);
        for (int i = t0; i < 192 * 160; i += 7168) wb2[i]  = f2b(w2[i]);
        for (int i = t0; i < 256 * 224; i += 7168) wfn0[i] = f2b(f0[i]);
        for (int i = t0; i < 256 * 256; i += 7168) wfn1[i] = f2b(f1[i]);
        if (t0 < 96) wd0[t0] = w0[t0 * 65 + 64];
        return;
    }
    __shared__ float W0s[96 * 65];
    __shared__ float xs[64 * 32];
    const int r0 = blk * 64;
    for (int i = t; i < 96 * 65; i += 256) W0s[i] = w0[i];
    for (int i = t; i < 2048; i += 256) xs[i] = x[(size_t)r0 * 32 + i];
    __syncthreads();
    for (int it = 0; it < 48; ++it) {              // 64 rows * 192 outs
        const int out = t + 256 * it;
        const int row = out / 192, oi = out - row * 192;
        const int o = (oi < 96) ? oi : oi - 96;
        const float* wr = W0s + o * 65 + ((oi < 96) ? 0 : 32);
        const float* xr = xs + row * 32;
        float a = (oi < 96) ? b0[o] : 0.0f;
#pragma unroll
        for (int k = 0; k < 32; ++k) a += wr[k] * xr[k];
        if (oi < 96) base0T[(size_t)(r0 + row) * 96 + o] = a;
        else         GT[(size_t)(r0 + row) * 96 + o] = a;
    }
    for (int i = t; i < 128; i += 256)
        xyt[(r0 + (i >> 1)) * 2 + (i & 1)] = xs[(i >> 1) * 32 + (i & 1)];
    for (int i = t; i < 2048; i += 256)
        hin[(size_t)(r0 + (i >> 5)) * 256 + 192 + (i & 31)] = xs[i];
}

// ---------------- edge kernel: one block per (b,i) -------------------------
// H1[112][96] (stride 104) built elementwise from tables; L2/L3 MFMA in
// 3 m-subsets {48,48,16} sharing H2l[48][168].  LDS 40.2 KB.
// NOTE: __launch_bounds__(256,3) NOT (256,4): the 4-waves/EU clamp made the
// compiler cap VGPR at 64 -> ~45 regs/thread spilled to scratch -> 249 MB of
// HBM spill writes/dispatch (R4: 400us, WRITE_SIZE 249MB). With <=170 budget
// the kernel fits in ~100 VGPR and 4 blocks/CU still fit (4w/SIMD * ~100 <= 512).
__global__ __launch_bounds__(256, 3) void edge_kernel(
    const float* __restrict__ base0T, const float* __restrict__ GT,
    const float* __restrict__ xyt, const float* __restrict__ wd0,
    const float* __restrict__ b1f, const float* __restrict__ eb2,
    const uint16_t* __restrict__ wb1, const uint16_t* __restrict__ wb2,
    float* __restrict__ hin)
{
    __shared__ __align__(16) uint16_t H1[112 * 104];   // 23296 B
    __shared__ __align__(16) uint16_t H2l[48 * 168];   // 16128 B
    __shared__ __align__(16) float b0wd[192];          // 768 B

    const int bi = blockIdx.x, b = bi / 100;
    const int t = threadIdx.x;
    const int lane = t & 63, wave = t >> 6;
    const int col = lane & 15, g = lane >> 4;

    if (t < 96) b0wd[t] = base0T[(size_t)bi * 96 + t];
    else if (t < 192) b0wd[t] = wd0[t - 96];
    const float xix = xyt[bi * 2 + 0], xiy = xyt[bi * 2 + 1];
    __syncthreads();

    // ---- H1 build: H1[j][o] = bf16(lrelu(G[j][o] + base0[o] + wd[o]*d_j))
    for (int it = 0; it < 11; ++it) {
        const int q = t + 256 * it;
        if (q < 2688) {                       // 112 rows * 24 o-quads
            const int j = q / 24, o4 = q - j * 24;
            uint32_t lo = 0, hi = 0;
            if (j < 100) {
                const float4 gv = *(const float4*)(GT + (size_t)(b * 100 + j) * 96 + o4 * 4);
                const float2 p = *(const float2*)(xyt + (b * 100 + j) * 2);
                const float dx = p.x - xix + 1e-12f, dy = p.y - xiy + 1e-12f;
                const float d = sqrtf(dx * dx + dy * dy);
                const float4 bb = *(const float4*)(b0wd + o4 * 4);
                const float4 wv = *(const float4*)(b0wd + 96 + o4 * 4);
                lo = pk2(lrelu(gv.x + bb.x + wv.x * d), lrelu(gv.y + bb.y + wv.y * d));
                hi = pk2(lrelu(gv.z + bb.z + wv.z * d), lrelu(gv.w + bb.w + wv.w * d));
            }
            *(uint2*)(H1 + j * 104 + o4 * 4) = (uint2){lo, hi};
        }
    }
    __syncthreads();

    float* hinrow = hin + (size_t)bi * 256;
    float ssum[3] = {0.f, 0.f, 0.f};
#pragma unroll
    for (int sub = 0; sub < 3; ++sub) {
        const int MT = (sub < 2) ? 3 : 1;
        {   // ---- L2: H2l = lrelu(H1[sub rows] @ W1^T + b1) ----
            f32x4 acc[3][3];
#pragma unroll
            for (int s = 0; s < 3; ++s) {
                const int nt = wave + 4 * s;
                if (nt < 10) {
                    const float bv = b1f[nt * 16 + col];
#pragma unroll
                    for (int m = 0; m < 3; ++m) if (m < MT)
                        acc[s][m] = (f32x4){bv, bv, bv, bv};
                }
            }
            __builtin_amdgcn_s_setprio(1);
#pragma unroll
            for (int kt = 0; kt < 3; ++kt) {
                bf16x8 bfr[3];
#pragma unroll
                for (int s = 0; s < 3; ++s) {
                    const int nt = wave + 4 * s;
                    if (nt < 10)
                        bfr[s] = *(const bf16x8*)(wb1 + (size_t)(nt * 16 + col) * 96 + kt * 32 + 8 * g);
                }
#pragma unroll
                for (int m = 0; m < 3; ++m) if (m < MT) {
                    const bf16x8 af = *(const bf16x8*)(H1 + (sub * 48 + m * 16 + col) * 104 + kt * 32 + 8 * g);
#pragma unroll
                    for (int s = 0; s < 3; ++s) {
                        const int nt = wave + 4 * s;
                        if (nt < 10)
                            acc[s][m] = __builtin_amdgcn_mfma_f32_16x16x32_bf16(af, bfr[s], acc[s][m], 0, 0, 0);
                    }
                }
            }
            __builtin_amdgcn_s_setprio(0);
#pragma unroll
            for (int s = 0; s < 3; ++s) {
                const int nt = wave + 4 * s;
                if (nt < 10) {
#pragma unroll
                    for (int m = 0; m < 3; ++m) if (m < MT)
#pragma unroll
                        for (int r = 0; r < 4; ++r)
                            H2l[(m * 16 + 4 * g + r) * 168 + nt * 16 + col] =
                                f2b(lrelu(acc[s][m][r]));
                }
            }
        }
        __syncthreads();
        {   // ---- L3 partial: ssum += masked row-sums of lrelu(H2l @ W2^T + b2)
            f32x4 acc[3][3];
#pragma unroll
            for (int s = 0; s < 3; ++s) {
                const float bv = eb2[(wave + 4 * s) * 16 + col];
#pragma unroll
                for (int m = 0; m < 3; ++m) if (m < MT)
                    acc[s][m] = (f32x4){bv, bv, bv, bv};
            }
            __builtin_amdgcn_s_setprio(1);
#pragma unroll
            for (int kt = 0; kt < 5; ++kt) {
                bf16x8 bfr[3];
#pragma unroll
                for (int s = 0; s < 3; ++s)
                    bfr[s] = *(const bf16x8*)(wb2 + (size_t)((wave + 4 * s) * 16 + col) * 160 + kt * 32 + 8 * g);
#pragma unroll
                for (int m = 0; m < 3; ++m) if (m < MT) {
                    const bf16x8 af = *(const bf16x8*)(H2l + (m * 16 + col) * 168 + kt * 32 + 8 * g);
#pragma unroll
                    for (int s = 0; s < 3; ++s)
                        acc[s][m] = __builtin_amdgcn_mfma_f32_16x16x32_bf16(af, bfr[s], acc[s][m], 0, 0, 0);
                }
            }
            __builtin_amdgcn_s_setprio(0);
#pragma unroll
            for (int s = 0; s < 3; ++s) {
                float ps = 0.0f;
#pragma unroll
                for (int m = 0; m < 3; ++m) if (m < MT) {
                    const int rowbase = sub * 48 + m * 16 + 4 * g;
#pragma unroll
                    for (int r = 0; r < 4; ++r)
                        if (sub < 2 || (rowbase + r < 100)) ps += lrelu(acc[s][m][r]);
                }
                ssum[s] += ps;
            }
        }
        if (sub < 2) __syncthreads();
    }
#pragma unroll
    for (int s = 0; s < 3; ++s) {
        float v = ssum[s];
        v += __shfl_xor(v, 16);
        v += __shfl_xor(v, 32);
        if (lane < 16) hinrow[(wave + 4 * s) * 16 + col] = v;
    }
}

// ---------------- fused node MLP: 16 rows per block, 400 blocks ------------
__global__ __launch_bounds__(256) void node_kernel(
    const float* __restrict__ hin,
    const uint16_t* __restrict__ wfn0, const float* __restrict__ fb0,
    const uint16_t* __restrict__ wfn1, const float* __restrict__ fb1,
    const float* __restrict__ fw2, const float* __restrict__ fb2,
    float* __restrict__ out)
{
    __shared__ __align__(16) uint16_t RA[16 * 264];
    __shared__ __align__(16) uint16_t RH[16 * 264];
    const int t = threadIdx.x, lane = t & 63, wave = t >> 6;
    const int col = lane & 15, g = lane >> 4;
    const int r0 = blockIdx.x * 16;

    for (int r = wave; r < 16; r += 4) {
        const float* src = hin + (size_t)(r0 + r) * 256;
        for (int c = lane; c < 224; c += 64)
            RA[r * 232 + c] = f2b(src[c]);
    }
    __syncthreads();
    {   // L0: 224 -> 256
        f32x4 acc[4];
#pragma unroll
        for (int s = 0; s < 4; ++s) {
            const float bv = fb0[(wave + 4 * s) * 16 + col];
            acc[s] = (f32x4){bv, bv, bv, bv};
        }
#pragma unroll
        for (int kt = 0; kt < 7; ++kt) {
            const bf16x8 af = *(const bf16x8*)(RA + col * 232 + kt * 32 + 8 * g);
#pragma unroll
            for (int s = 0; s < 4; ++s) {
                const bf16x8 bfr = *(const bf16x8*)(
                    wfn0 + (size_t)((wave + 4 * s) * 16 + col) * 224 + kt * 32 + 8 * g);
                acc[s] = __builtin_amdgcn_mfma_f32_16x16x32_bf16(af, bfr, acc[s], 0, 0, 0);
            }
        }
#pragma unroll
        for (int s = 0; s < 4; ++s)
#pragma unroll
            for (int r = 0; r < 4; ++r)
                RH[(4 * g + r) * 264 + (wave + 4 * s) * 16 + col] = f2b(lrelu(acc[s][r]));
    }
    __syncthreads();
    {   // L1: 256 -> 256
        f32x4 acc[4];
#pragma unroll
        for (int s = 0; s < 4; ++s) {
            const float bv = fb1[(wave + 4 * s) * 16 + col];
            acc[s] = (f32x4){bv, bv, bv, bv};
        }
#pragma unroll
        for (int kt = 0; kt < 8; ++kt) {
            const bf16x8 af = *(const bf16x8*)(RH + col * 264 + kt * 32 + 8 * g);
#pragma unroll
            for (int s = 0; s < 4; ++s) {
                const bf16x8 bfr = *(const bf16x8*)(
                    wfn1 + (size_t)((wave + 4 * s) * 16 + col) * 256 + kt * 32 + 8 * g);
                acc[s] = __builtin_amdgcn_mfma_f32_16x16x32_bf16(af, bfr, acc[s], 0, 0, 0);
            }
        }
        __syncthreads();
#pragma unroll
        for (int s = 0; s < 4; ++s)
#pragma unroll
            for (int r = 0; r < 4; ++r)
                RA[(4 * g + r) * 264 + (wave + 4 * s) * 16 + col] = f2b(lrelu(acc[s][r]));
    }
    __syncthreads();
    // L2 final: 3 outputs fp32 + tanh
    const int row = t >> 4, u = t & 15;
    float h = 0.0f;
    if (u < 12) {
        const int o = u >> 2, ks = u & 3;
        const float* w = fw2 + o * 256 + ks * 64;
        const uint16_t* hr = RA + row * 264 + ks * 64;
        float a = 0.0f;
#pragma unroll 8
        for (int k = 0; k < 64; k += 4) {
            const ushort4 hv = *(const ushort4*)(hr + k);
            a += w[k + 0] * b2f16(hv.x) + w[k + 1] * b2f16(hv.y)
               + w[k + 2] * b2f16(hv.z) + w[k + 3] * b2f16(hv.w);
        }
        h = a;
    }
    h += __shfl_xor(h, 1);
    h += __shfl_xor(h, 2);
    if (u < 12 && (u & 3) == 0)
        out[(size_t)(r0 + row) * 3 + (u >> 2)] = tanhf(h + fb2[u >> 2]);
}

extern "C" void kernel_launch(void* const* d_in, const int* in_sizes, int n_in,
                              void* d_out, int out_size, void* d_ws, size_t ws_size,
                              hipStream_t stream) {
    (void)in_sizes; (void)n_in; (void)out_size; (void)ws_size;
    const float* x     = (const float*)d_in[0];
    const float* fe_w0 = (const float*)d_in[1];
    const float* fe_b0 = (const float*)d_in[2];
    const float* fe_w1 = (const float*)d_in[3];
    const float* fe_b1 = (const float*)d_in[4];
    const float* fe_w2 = (const float*)d_in[5];
    const float* fe_b2 = (const float*)d_in[6];
    const float* fn_w0 = (const float*)d_in[7];
    const float* fn_b0 = (const float*)d_in[8];
    const float* fn_w1 = (const float*)d_in[9];
    const float* fn_b1 = (const float*)d_in[10];
    const float* fn_w2 = (const float*)d_in[11];
    const float* fn_b2 = (const float*)d_in[12];
    float* out = (float*)d_out;

    float* buf0   = (float*)d_ws;                     // hin [6400][256] f32
    float* base0T = buf0 + (size_t)6400 * 256;        // 6400*96
    float* GT     = base0T + 6400 * 96;               // 6400*96
    float* xyt    = GT + 6400 * 96;                   // 6400*2
    float* wd0    = xyt + 12800;                      // 96 (pad 128)
    uint16_t* wb1  = (uint16_t*)(wd0 + 128);          // 160*96
    uint16_t* wb2  = wb1 + 160 * 96;                  // 192*160
    uint16_t* wfn0 = wb2 + 192 * 160;                 // 256*224
    uint16_t* wfn1 = wfn0 + 256 * 224;                // 256*256

    precompute<<<128, 256, 0, stream>>>(x, fe_w0, fe_b0, fe_w1, fe_w2,
                                        fn_w0, fn_w1,
                                        base0T, GT, xyt, wd0,
                                        wb1, wb2, wfn0, wfn1, buf0);
    edge_kernel<<<6400, 256, 0, stream>>>(base0T, GT, xyt, wd0,
                                          fe_b1, fe_b2, wb1, wb2, buf0);
    node_kernel<<<400, 256, 0, stream>>>(buf0, wfn0, fn_b0, wfn1, fn_b1,
                                         fn_w2, fn_b2, out);
}

// Round 6
// 168.948 us; speedup vs baseline: 2.4572x; 1.2800x over previous
//
#include <hip/hip_runtime.h>
#include <math.h>

#define ALPHA 0.2f

typedef __attribute__((ext_vector_type(8))) short bf16x8;
typedef __attribute__((ext_vector_type(4))) float f32x4;

static __device__ __forceinline__ float lrelu(float v) {
    return fmaxf(v, ALPHA * v);   // 2 VALU (mul+max), branchless
}
// fp32 -> bf16 RTNE (software; used only in low-volume kernels)
static __device__ __forceinline__ uint16_t f2b(float f) {
    union { float f; uint32_t u; } c; c.f = f;
    const uint32_t u = c.u + 0x7FFFu + ((c.u >> 16) & 1u);
    return (uint16_t)(u >> 16);
}
// HW packed cvt: low16 = bf16(lo), high16 = bf16(hi), RTNE
static __device__ __forceinline__ uint32_t cvt2(float lo, float hi) {
    uint32_t r;
    asm("v_cvt_pk_bf16_f32 %0, %1, %2" : "=v"(r) : "v"(lo), "v"(hi));
    return r;
}

// ---------------- precompute: tables + bf16 weights (once per call) --------
__global__ __launch_bounds__(256) void precompute(
    const float* __restrict__ x, const float* __restrict__ w0,
    const float* __restrict__ b0, const float* __restrict__ w1,
    const float* __restrict__ w2, const float* __restrict__ f0,
    const float* __restrict__ f1,
    float* __restrict__ base0T, float* __restrict__ GT,
    float* __restrict__ xyt, float* __restrict__ wd0,
    uint16_t* __restrict__ wb1, uint16_t* __restrict__ wb2,
    uint16_t* __restrict__ wfn0, uint16_t* __restrict__ wfn1,
    float* __restrict__ hin)
{
    const int blk = blockIdx.x, t = threadIdx.x;
    if (blk >= 100) {
        const int t0 = (blk - 100) * 256 + t;  // 0..7167
        for (int i = t0; i < 160 * 96;  i += 7168) wb1[i]  = f2b(w1[i]);
        for (int i = t0; i < 192 * 160; i += 7168) wb2[i]  = f2b(w2[i]);
        for (int i = t0; i < 256 * 224; i += 7168) wfn0[i] = f2b(f0[i]);
        for (int i = t0; i < 256 * 256; i += 7168) wfn1[i] = f2b(f1[i]);
        if (t0 < 96) wd0[t0] = w0[t0 * 65 + 64];
        return;
    }
    __shared__ float W0s[96 * 65];
    __shared__ float xs[64 * 32];
    const int r0 = blk * 64;
    for (int i = t; i < 96 * 65; i += 256) W0s[i] = w0[i];
    for (int i = t; i < 2048; i += 256) xs[i] = x[(size_t)r0 * 32 + i];
    __syncthreads();
    for (int it = 0; it < 48; ++it) {              // 64 rows * 192 outs
        const int out = t + 256 * it;
        const int row = out / 192, oi = out - row * 192;
        const int o = (oi < 96) ? oi : oi - 96;
        const float* wr = W0s + o * 65 + ((oi < 96) ? 0 : 32);
        const float* xr = xs + row * 32;
        float a = (oi < 96) ? b0[o] : 0.0f;
#pragma unroll
        for (int k = 0; k < 32; ++k) a += wr[k] * xr[k];
        if (oi < 96) base0T[(size_t)(r0 + row) * 96 + o] = a;
        else         GT[(size_t)(r0 + row) * 96 + o] = a;
    }
    for (int i = t; i < 128; i += 256)
        xyt[(r0 + (i >> 1)) * 2 + (i & 1)] = xs[(i >> 1) * 32 + (i & 1)];
    for (int i = t; i < 2048; i += 256)
        hin[(size_t)(r0 + (i >> 5)) * 256 + 192 + (i & 31)] = xs[i];
}

// ---------------- edge kernel: TWO blocks per (b,i), split over j ----------
// blockIdx = bi*2 + half.  half 0: j 0..63 (MT=4) -> writes hin[bi][0..191];
// half 1: j 64..99 (48 rows padded, MT=3) -> writes PB[bi][0..191].
// Structure per block: build H1 (reg->LDS, b128 stores) | barrier |
// L2 MFMA -> H2l | barrier | L3 MFMA + masked row-sum -> global.
// LDS 34.8 KB -> 4 blocks/CU.  Only 2 barriers per block.
__global__ __launch_bounds__(256, 3) void edge_kernel(
    const float* __restrict__ base0T, const float* __restrict__ GT,
    const float* __restrict__ xyt, const float* __restrict__ wd0,
    const float* __restrict__ b1f, const float* __restrict__ eb2,
    const uint16_t* __restrict__ wb1, const uint16_t* __restrict__ wb2,
    float* __restrict__ hin, float* __restrict__ PB)
{
    __shared__ __align__(16) uint16_t H1[64 * 104];    // 13312 B (stride 104: 13x16B, odd -> 2-way)
    __shared__ __align__(16) uint16_t H2l[64 * 168];   // 21504 B (stride 168: 21x16B, odd -> 2-way)

    const int bi = blockIdx.x >> 1, half = blockIdx.x & 1;
    const int b = bi / 100;
    const int MT = half ? 3 : 4;
    const int j0 = half * 64;
    const int t = threadIdx.x, lane = t & 63, wave = t >> 6;
    const int col = lane & 15, g = lane >> 4;

    // ---- H1 build: 4 threads per row, 24 cols each; HW cvt_pk; b128 stores
    {
        const int row = t >> 2, ch = t & 3;
        if (row < MT * 16) {
            const int jl = j0 + row;
            uint16_t* dst = H1 + row * 104 + ch * 24;
            if (jl < 100) {
                const int jg = b * 100 + jl;
                const float2 p  = *(const float2*)(xyt + 2 * jg);
                const float2 pi = *(const float2*)(xyt + 2 * bi);
                const float dx = p.x - pi.x + 1e-12f, dy = p.y - pi.y + 1e-12f;
                const float d = sqrtf(dx * dx + dy * dy);
                const float* gr = GT + (size_t)jg * 96 + ch * 24;
                const float* bb = base0T + (size_t)bi * 96 + ch * 24;
                const float* wv = wd0 + ch * 24;
                uint32_t pk[12];
#pragma unroll
                for (int q = 0; q < 6; ++q) {
                    const f32x4 gq = *(const f32x4*)(gr + q * 4);
                    const f32x4 bq = *(const f32x4*)(bb + q * 4);
                    const f32x4 wq = *(const f32x4*)(wv + q * 4);
                    float v[4];
#pragma unroll
                    for (int e = 0; e < 4; ++e)
                        v[e] = lrelu(gq[e] + bq[e] + wq[e] * d);
                    pk[2 * q]     = cvt2(v[0], v[1]);
                    pk[2 * q + 1] = cvt2(v[2], v[3]);
                }
#pragma unroll
                for (int q = 0; q < 3; ++q)
                    *(uint4*)(dst + q * 8) =
                        (uint4){pk[4 * q], pk[4 * q + 1], pk[4 * q + 2], pk[4 * q + 3]};
            } else {
                const uint4 z = {0u, 0u, 0u, 0u};
#pragma unroll
                for (int q = 0; q < 3; ++q) *(uint4*)(dst + q * 8) = z;
            }
        }
    }
    __syncthreads();

    // ---- L2: H2l = lrelu(H1 @ W1^T + b1)   (N=160 -> 10 nt over 12 slots)
    {
        f32x4 acc[3][4];
#pragma unroll
        for (int s = 0; s < 3; ++s) {
            const int nt = wave + 4 * s;
            if (nt < 10) {
                const float bv = b1f[nt * 16 + col];
#pragma unroll
                for (int m = 0; m < 4; ++m) if (m < MT)
                    acc[s][m] = (f32x4){bv, bv, bv, bv};
            }
        }
        __builtin_amdgcn_s_setprio(1);
#pragma unroll
        for (int kt = 0; kt < 3; ++kt) {
            bf16x8 bfr[3];
#pragma unroll
            for (int s = 0; s < 3; ++s) {
                const int nt = wave + 4 * s;
                if (nt < 10)
                    bfr[s] = *(const bf16x8*)(wb1 + (size_t)(nt * 16 + col) * 96 + kt * 32 + 8 * g);
            }
#pragma unroll
            for (int m = 0; m < 4; ++m) if (m < MT) {
                const bf16x8 af = *(const bf16x8*)(H1 + (m * 16 + col) * 104 + kt * 32 + 8 * g);
#pragma unroll
                for (int s = 0; s < 3; ++s) {
                    const int nt = wave + 4 * s;
                    if (nt < 10)
                        acc[s][m] = __builtin_amdgcn_mfma_f32_16x16x32_bf16(af, bfr[s], acc[s][m], 0, 0, 0);
                }
            }
        }
        __builtin_amdgcn_s_setprio(0);
#pragma unroll
        for (int s = 0; s < 3; ++s) {
            const int nt = wave + 4 * s;
            if (nt < 10) {
#pragma unroll
                for (int m = 0; m < 4; ++m) if (m < MT) {
                    const uint32_t p01 = cvt2(lrelu(acc[s][m][0]), lrelu(acc[s][m][1]));
                    const uint32_t p23 = cvt2(lrelu(acc[s][m][2]), lrelu(acc[s][m][3]));
                    const int base = (m * 16 + 4 * g) * 168 + nt * 16 + col;
                    H2l[base]       = (uint16_t)p01;
                    H2l[base + 168] = (uint16_t)(p01 >> 16);
                    H2l[base + 336] = (uint16_t)p23;
                    H2l[base + 504] = (uint16_t)(p23 >> 16);
                }
            }
        }
    }
    __syncthreads();

    // ---- L3: masked row-sum of lrelu(H2l @ W2^T + b2)  (N=192, 12 slots)
    float ssum[3] = {0.f, 0.f, 0.f};
    {
        f32x4 acc[3][4];
#pragma unroll
        for (int s = 0; s < 3; ++s) {
            const float bv = eb2[(wave + 4 * s) * 16 + col];
#pragma unroll
            for (int m = 0; m < 4; ++m) if (m < MT)
                acc[s][m] = (f32x4){bv, bv, bv, bv};
        }
        __builtin_amdgcn_s_setprio(1);
#pragma unroll
        for (int kt = 0; kt < 5; ++kt) {
            bf16x8 bfr[3];
#pragma unroll
            for (int s = 0; s < 3; ++s)
                bfr[s] = *(const bf16x8*)(wb2 + (size_t)((wave + 4 * s) * 16 + col) * 160 + kt * 32 + 8 * g);
#pragma unroll
            for (int m = 0; m < 4; ++m) if (m < MT) {
                const bf16x8 af = *(const bf16x8*)(H2l + (m * 16 + col) * 168 + kt * 32 + 8 * g);
#pragma unroll
                for (int s = 0; s < 3; ++s)
                    acc[s][m] = __builtin_amdgcn_mfma_f32_16x16x32_bf16(af, bfr[s], acc[s][m], 0, 0, 0);
            }
        }
        __builtin_amdgcn_s_setprio(0);
#pragma unroll
        for (int s = 0; s < 3; ++s) {
#pragma unroll
            for (int m = 0; m < 4; ++m) if (m < MT) {
                // half 1, m==2 covers local rows 32..47 = j 96..111: keep only g==0 (j 96..99)
                const bool rowok = (MT == 4) || (m < 2) || (g == 0);
                if (rowok) {
#pragma unroll
                    for (int r = 0; r < 4; ++r) ssum[s] += lrelu(acc[s][m][r]);
                }
            }
        }
    }
    float* dst = (half == 0) ? (hin + (size_t)bi * 256) : (PB + (size_t)bi * 192);
#pragma unroll
    for (int s = 0; s < 3; ++s) {
        float v = ssum[s];
        v += __shfl_xor(v, 16);
        v += __shfl_xor(v, 32);
        if (lane < 16) dst[(wave + 4 * s) * 16 + col] = v;
    }
}

// ---------------- fused node MLP: 16 rows per block, 400 blocks ------------
__global__ __launch_bounds__(256) void node_kernel(
    const float* __restrict__ hin, const float* __restrict__ PB,
    const uint16_t* __restrict__ wfn0, const float* __restrict__ fb0,
    const uint16_t* __restrict__ wfn1, const float* __restrict__ fb1,
    const float* __restrict__ fw2, const float* __restrict__ fb2,
    float* __restrict__ out)
{
    __shared__ __align__(16) uint16_t RA[16 * 264];
    __shared__ __align__(16) uint16_t RH[16 * 264];
    const int t = threadIdx.x, lane = t & 63, wave = t >> 6;
    const int col = lane & 15, g = lane >> 4;
    const int r0 = blockIdx.x * 16;

    for (int r = wave; r < 16; r += 4) {
        const float* src = hin + (size_t)(r0 + r) * 256;
        const float* pbr = PB + (size_t)(r0 + r) * 192;
        for (int c = lane; c < 224; c += 64) {
            float v = src[c];
            if (c < 192) v += pbr[c];          // combine the two j-half partials
            RA[r * 232 + c] = f2b(v);
        }
    }
    __syncthreads();
    {   // L0: 224 -> 256
        f32x4 acc[4];
#pragma unroll
        for (int s = 0; s < 4; ++s) {
            const float bv = fb0[(wave + 4 * s) * 16 + col];
            acc[s] = (f32x4){bv, bv, bv, bv};
        }
#pragma unroll
        for (int kt = 0; kt < 7; ++kt) {
            const bf16x8 af = *(const bf16x8*)(RA + col * 232 + kt * 32 + 8 * g);
#pragma unroll
            for (int s = 0; s < 4; ++s) {
                const bf16x8 bfr = *(const bf16x8*)(
                    wfn0 + (size_t)((wave + 4 * s) * 16 + col) * 224 + kt * 32 + 8 * g);
                acc[s] = __builtin_amdgcn_mfma_f32_16x16x32_bf16(af, bfr, acc[s], 0, 0, 0);
            }
        }
#pragma unroll
        for (int s = 0; s < 4; ++s)
#pragma unroll
            for (int r = 0; r < 4; ++r)
                RH[(4 * g + r) * 264 + (wave + 4 * s) * 16 + col] = f2b(lrelu(acc[s][r]));
    }
    __syncthreads();
    {   // L1: 256 -> 256
        f32x4 acc[4];
#pragma unroll
        for (int s = 0; s < 4; ++s) {
            const float bv = fb1[(wave + 4 * s) * 16 + col];
            acc[s] = (f32x4){bv, bv, bv, bv};
        }
#pragma unroll
        for (int kt = 0; kt < 8; ++kt) {
            const bf16x8 af = *(const bf16x8*)(RH + col * 264 + kt * 32 + 8 * g);
#pragma unroll
            for (int s = 0; s < 4; ++s) {
                const bf16x8 bfr = *(const bf16x8*)(
                    wfn1 + (size_t)((wave + 4 * s) * 16 + col) * 256 + kt * 32 + 8 * g);
                acc[s] = __builtin_amdgcn_mfma_f32_16x16x32_bf16(af, bfr, acc[s], 0, 0, 0);
            }
        }
        __syncthreads();
#pragma unroll
        for (int s = 0; s < 4; ++s)
#pragma unroll
            for (int r = 0; r < 4; ++r)
                RA[(4 * g + r) * 264 + (wave + 4 * s) * 16 + col] = f2b(lrelu(acc[s][r]));
    }
    __syncthreads();
    // L2 final: 3 outputs fp32 + tanh
    const int row = t >> 4, u = t & 15;
    float h = 0.0f;
    if (u < 12) {
        const int o = u >> 2, ks = u & 3;
        const float* w = fw2 + o * 256 + ks * 64;
        const uint16_t* hr = RA + row * 264 + ks * 64;
        float a = 0.0f;
#pragma unroll 8
        for (int k = 0; k < 64; k += 4) {
            const ushort4 hv = *(const ushort4*)(hr + k);
            union { uint32_t u; float f; } c0, c1, c2, c3;
            c0.u = (uint32_t)hv.x << 16; c1.u = (uint32_t)hv.y << 16;
            c2.u = (uint32_t)hv.z << 16; c3.u = (uint32_t)hv.w << 16;
            a += w[k] * c0.f + w[k + 1] * c1.f + w[k + 2] * c2.f + w[k + 3] * c3.f;
        }
        h = a;
    }
    h += __shfl_xor(h, 1);
    h += __shfl_xor(h, 2);
    if (u < 12 && (u & 3) == 0)
        out[(size_t)(r0 + row) * 3 + (u >> 2)] = tanhf(h + fb2[u >> 2]);
}

extern "C" void kernel_launch(void* const* d_in, const int* in_sizes, int n_in,
                              void* d_out, int out_size, void* d_ws, size_t ws_size,
                              hipStream_t stream) {
    (void)in_sizes; (void)n_in; (void)out_size; (void)ws_size;
    const float* x     = (const float*)d_in[0];
    const float* fe_w0 = (const float*)d_in[1];
    const float* fe_b0 = (const float*)d_in[2];
    const float* fe_w1 = (const float*)d_in[3];
    const float* fe_b1 = (const float*)d_in[4];
    const float* fe_w2 = (const float*)d_in[5];
    const float* fe_b2 = (const float*)d_in[6];
    const float* fn_w0 = (const float*)d_in[7];
    const float* fn_b0 = (const float*)d_in[8];
    const float* fn_w1 = (const float*)d_in[9];
    const float* fn_b1 = (const float*)d_in[10];
    const float* fn_w2 = (const float*)d_in[11];
    const float* fn_b2 = (const float*)d_in[12];
    float* out = (float*)d_out;

    float* buf0   = (float*)d_ws;                     // hin [6400][256] f32
    float* base0T = buf0 + (size_t)6400 * 256;        // 6400*96
    float* GT     = base0T + 6400 * 96;               // 6400*96
    float* xyt    = GT + 6400 * 96;                   // 6400*2
    float* wd0    = xyt + 12800;                      // 96 (pad 128)
    uint16_t* wb1  = (uint16_t*)(wd0 + 128);          // 160*96
    uint16_t* wb2  = wb1 + 160 * 96;                  // 192*160
    uint16_t* wfn0 = wb2 + 192 * 160;                 // 256*224
    uint16_t* wfn1 = wfn0 + 256 * 224;                // 256*256
    float* PB = (float*)(wfn1 + 256 * 256);           // [6400][192] f32 partials

    precompute<<<128, 256, 0, stream>>>(x, fe_w0, fe_b0, fe_w1, fe_w2,
                                        fn_w0, fn_w1,
                                        base0T, GT, xyt, wd0,
                                        wb1, wb2, wfn0, wfn1, buf0);
    edge_kernel<<<12800, 256, 0, stream>>>(base0T, GT, xyt, wd0,
                                           fe_b1, fe_b2, wb1, wb2, buf0, PB);
    node_kernel<<<400, 256, 0, stream>>>(buf0, PB, wfn0, fn_b0, wfn1, fn_b1,
                                         fn_w2, fn_b2, out);
}